// Round 4
// baseline (3410.924 us; speedup 1.0000x reference)
//
#include <hip/hip_runtime.h>
#include <hip/hip_bf16.h>

#define TPB 256
constexpr int B_ = 256, S_ = 512, D_ = 512, Q_ = 256, NM_ = 512;
constexpr int NB = 64, NT = 8;

typedef _Float16 f16x8 __attribute__((ext_vector_type(8)));
typedef float f32x4 __attribute__((ext_vector_type(4)));

// XCD-co-locating decode: x=bid&7 -> XCD; per XCD: tiles fastest, then cls, then group.
__device__ __forceinline__ void decode_mt(int bid, int W, int& m, int& t){
  int x = bid & 7, r = bid >> 3;
  t = r % W; int u = r / W;
  m = (((u >> 1)*8 + x) << 1) | (u & 1);
}

// pair-swizzled LDS accessor: pg = column-pair index, swizzle within 32-pair groups
__device__ __forceinline__ float2* pr2(float* base, int Wf, int row, int pg){
  int ph = (pg & ~31) | ((pg ^ row) & 31);
  return (float2*)(base + (size_t)row*Wf + ph*2);
}

// stage 64x64 f32 tile row-major into [64][68] padded LDS, 512 threads
__device__ __forceinline__ void stage68(const float* __restrict__ src, int ld,
                                        float* __restrict__ dst, int t){
  int r = t>>3, seg = (t&7)*8;
  const float4* s4 = (const float4*)(src + (size_t)r*ld + seg);
  float4 a = s4[0], b = s4[1];
  *((float4*)&dst[r*68+seg])   = a;
  *((float4*)&dst[r*68+seg+4]) = b;
}

// ---------------- stats: counts, means, pos bitmask ----------------
__global__ __launch_bounds__(TPB) void k_stats(const float* __restrict__ X,
                                               const int* __restrict__ labels,
                                               const int* __restrict__ slen,
                                               float* __restrict__ mu,
                                               float* __restrict__ cnt,
                                               unsigned int* __restrict__ wpbits)
{
  int b = blockIdx.x, t = threadIdx.x;
  __shared__ int lab[S_];
  __shared__ float red[TPB];
  int L = slen[b];
  for (int s = t; s < S_; s += TPB) {
    int lb = labels[b*S_ + s];
    lab[s] = (s < L) ? lb : -1;
  }
  __syncthreads();
  if (t < 16) {
    unsigned int wword = 0;
    for (int i2 = 0; i2 < 32; i2++) if (lab[t*32 + i2] == 1) wword |= (1u << i2);
    wpbits[b*16 + t] = wword;
  }
  int cpi=0, cni=0;
  for (int s=t; s<S_; s+=TPB){ cpi += (lab[s]==1); cni += (lab[s]==0); }
  red[t] = (float)cpi; __syncthreads();
  for (int o=TPB/2;o>0;o>>=1){ if(t<o) red[t]+=red[t+o]; __syncthreads(); }
  float cp = red[0]; __syncthreads();
  red[t] = (float)cni; __syncthreads();
  for (int o=TPB/2;o>0;o>>=1){ if(t<o) red[t]+=red[t+o]; __syncthreads(); }
  float cn = red[0];
  if (t==0){ cnt[b*2+0]=cn; cnt[b*2+1]=cp; }
  float sp0=0,sp1=0,sn0=0,sn1=0;
  const float* Xb = X + (size_t)b*S_*D_;
  for (int s=0;s<S_;s++){
    int e = lab[s];
    if (e < 0) continue;
    float x0 = Xb[(size_t)s*D_ + t];
    float x1 = Xb[(size_t)s*D_ + t + 256];
    if (e==1){ sp0+=x0; sp1+=x1; } else { sn0+=x0; sn1+=x1; }
  }
  float stv = (float)L;
  float* mb = mu + (size_t)b*3*D_;
  mb[0*D_ + t] = sn0/cn;        mb[0*D_ + t+256] = sn1/cn;
  mb[1*D_ + t] = sp0/cp;        mb[1*D_ + t+256] = sp1/cp;
  mb[2*D_ + t] = (sn0+sp0)/stv; mb[2*D_ + t+256] = (sn1+sp1)/stv;
}

// ---------------- prep: transpose X -> f16 hi/lo [B][D][S], valid-masked ----------------
__global__ __launch_bounds__(TPB) void k_prep(const float* __restrict__ X,
                                              const int* __restrict__ slen,
                                              unsigned short* __restrict__ Xvh,
                                              unsigned short* __restrict__ Xvl)
{
  int b = blockIdx.y, z = blockIdx.x;
  int d0 = (z>>3)*64, s0 = (z&7)*64;
  int t = threadIdx.x;
  __shared__ float Tl[64][65];
  const float* src = X + ((size_t)b*S_ + s0)*D_ + d0;
  { int r = t>>2, seg = (t&3)*16;
    const float4* s4 = (const float4*)(src + (size_t)r*D_ + seg);
    #pragma unroll
    for (int i=0;i<4;i++){ float4 v = s4[i];
      Tl[seg+i*4+0][r]=v.x; Tl[seg+i*4+1][r]=v.y; Tl[seg+i*4+2][r]=v.z; Tl[seg+i*4+3][r]=v.w; } }
  __syncthreads();
  int L = slen[b];
  int dr = t>>2, sc = (t&3)*16;
  union U16 { unsigned short u[8]; uint4 v; };
  U16 H[2], Lo[2];
  #pragma unroll
  for (int g=0; g<2; g++)
    #pragma unroll
    for (int i=0;i<8;i++){
      int si = sc + g*8 + i;
      float x = (s0+si < L) ? Tl[dr][si] : 0.f;
      _Float16 hh = (_Float16)x;
      float lo = x - (float)hh;
      H[g].u[i]  = __builtin_bit_cast(unsigned short, hh);
      Lo[g].u[i] = __builtin_bit_cast(unsigned short, (_Float16)lo);
    }
  size_t o = ((size_t)b*D_ + d0+dr)*S_ + s0 + sc;
  *(uint4*)(Xvh+o)   = H[0].v;  *(uint4*)(Xvh+o+8) = H[1].v;
  *(uint4*)(Xvl+o)   = Lo[0].v; *(uint4*)(Xvl+o+8) = Lo[1].v;
}

// ---------------- MFMA Gram -> A matrices (upper 128-tiles incl. diagonal) ----------------
__global__ __launch_bounds__(TPB,2) void k_gram(const unsigned short* __restrict__ Xvh,
                                                const unsigned short* __restrict__ Xvl,
                                                const unsigned int* __restrict__ wpbits,
                                                const float* __restrict__ mu,
                                                const float* __restrict__ cnt,
                                                const int* __restrict__ slen,
                                                float* __restrict__ A)
{
  __shared__ unsigned short sAvh[128][32], sAvl[128][32], sAph[128][32], sApl[128][32],
                            sBvh[128][32], sBvl[128][32];
  int id = blockIdx.x;
  int g = id>>3;
  int b = (g/10)*8 + (id&7);
  int z = g%10;
  int ti=0; while (z >= 4-ti){ z -= 4-ti; ti++; } int tj = ti + z;
  int i0 = ti*128, j0 = tj*128;
  int t = threadIdx.x, lane = t&63, w = t>>6;
  int wr = w>>1, wc = w&1, l15 = lane&15;

  f32x4 acc_t[4][4], acc_p[4][4];
  f32x4 z4 = {0.f,0.f,0.f,0.f};
  #pragma unroll
  for (int mf=0;mf<4;mf++)
    #pragma unroll
    for (int nf=0;nf<4;nf++){ acc_t[mf][nf]=z4; acc_p[mf][nf]=z4; }

  const size_t baseA = ((size_t)b*D_ + i0)*S_;
  const size_t baseB = ((size_t)b*D_ + j0)*S_;
  int phx = (lane>>4) ^ ((l15>>1)&3);

  for (int ks=0; ks<16; ks++){
    int s0 = ks*32;
    unsigned int wpw = wpbits[b*16 + ks];
    __syncthreads();
    #pragma unroll
    for (int h=0; h<2; h++){
      int ci = t + h*256;
      int row = ci>>2, cpos = ci&3;
      int ph = cpos ^ ((row>>1)&3);
      size_t ga = baseA + (size_t)row*S_ + s0 + cpos*8;
      size_t gb = baseB + (size_t)row*S_ + s0 + cpos*8;
      uint4 vh = *(const uint4*)(Xvh+ga);
      uint4 vl = *(const uint4*)(Xvl+ga);
      uint4 bh = *(const uint4*)(Xvh+gb);
      uint4 bl = *(const uint4*)(Xvl+gb);
      unsigned int m8 = (wpw >> (cpos*8)) & 0xFFu;
      uint4 mk;
      mk.x = ((m8&1u)?0xFFFFu:0u)  | ((m8&2u)?0xFFFF0000u:0u);
      mk.y = ((m8&4u)?0xFFFFu:0u)  | ((m8&8u)?0xFFFF0000u:0u);
      mk.z = ((m8&16u)?0xFFFFu:0u) | ((m8&32u)?0xFFFF0000u:0u);
      mk.w = ((m8&64u)?0xFFFFu:0u) | ((m8&128u)?0xFFFF0000u:0u);
      uint4 p4, q4;
      p4.x = vh.x&mk.x; p4.y = vh.y&mk.y; p4.z = vh.z&mk.z; p4.w = vh.w&mk.w;
      q4.x = vl.x&mk.x; q4.y = vl.y&mk.y; q4.z = vl.z&mk.z; q4.w = vl.w&mk.w;
      *(uint4*)&sAvh[row][ph*8] = vh;
      *(uint4*)&sAvl[row][ph*8] = vl;
      *(uint4*)&sAph[row][ph*8] = p4;
      *(uint4*)&sApl[row][ph*8] = q4;
      *(uint4*)&sBvh[row][ph*8] = bh;
      *(uint4*)&sBvl[row][ph*8] = bl;
    }
    __syncthreads();
    f16x8 Avh[4], Avl[4], Aph[4], Apl[4];
    #pragma unroll
    for (int mf=0;mf<4;mf++){
      int r = wr*64 + mf*16 + l15;
      Avh[mf] = __builtin_bit_cast(f16x8, *(const uint4*)&sAvh[r][phx*8]);
      Avl[mf] = __builtin_bit_cast(f16x8, *(const uint4*)&sAvl[r][phx*8]);
      Aph[mf] = __builtin_bit_cast(f16x8, *(const uint4*)&sAph[r][phx*8]);
      Apl[mf] = __builtin_bit_cast(f16x8, *(const uint4*)&sApl[r][phx*8]);
    }
    #pragma unroll
    for (int nf=0;nf<4;nf++){
      int r = wc*64 + nf*16 + l15;
      f16x8 Bh = __builtin_bit_cast(f16x8, *(const uint4*)&sBvh[r][phx*8]);
      f16x8 Bl = __builtin_bit_cast(f16x8, *(const uint4*)&sBvl[r][phx*8]);
      #pragma unroll
      for (int mf=0;mf<4;mf++){
        acc_t[mf][nf] = __builtin_amdgcn_mfma_f32_16x16x32_f16(Avh[mf], Bh, acc_t[mf][nf],0,0,0);
        acc_t[mf][nf] = __builtin_amdgcn_mfma_f32_16x16x32_f16(Avh[mf], Bl, acc_t[mf][nf],0,0,0);
        acc_t[mf][nf] = __builtin_amdgcn_mfma_f32_16x16x32_f16(Avl[mf], Bh, acc_t[mf][nf],0,0,0);
        acc_p[mf][nf] = __builtin_amdgcn_mfma_f32_16x16x32_f16(Aph[mf], Bh, acc_p[mf][nf],0,0,0);
        acc_p[mf][nf] = __builtin_amdgcn_mfma_f32_16x16x32_f16(Aph[mf], Bl, acc_p[mf][nf],0,0,0);
        acc_p[mf][nf] = __builtin_amdgcn_mfma_f32_16x16x32_f16(Apl[mf], Bh, acc_p[mf][nf],0,0,0);
      }
    }
  }
  float cn = cnt[b*2+0], cp = cnt[b*2+1];
  float stv = (float)slen[b];
  float kn = 0.1f/(cn-1.f), kp = 0.1f/(cp-1.f), kt = 0.9f/(stv-1.f);
  float rn = 0.1f*cn/(cn-1.f), rp = 0.1f*cp/(cp-1.f), rt = 0.9f*stv/(stv-1.f);
  const float* mb = mu + (size_t)b*3*D_;
  float* A0 = A + (size_t)(b*2+0)*D_*D_;
  float* A1 = A + (size_t)(b*2+1)*D_*D_;
  int rbase = i0 + wr*64 + (lane>>4)*4;
  int cbase = j0 + wc*64 + l15;
  #pragma unroll
  for (int mf=0;mf<4;mf++){
    #pragma unroll
    for (int i=0;i<4;i++){
      int r = rbase + mf*16 + i;
      float mnr = mb[r], mpr = mb[D_+r], mtr = mb[2*D_+r];
      #pragma unroll
      for (int nf=0;nf<4;nf++){
        int c = cbase + nf*16;
        float mnc = mb[c], mpc = mb[D_+c], mtc = mb[2*D_+c];
        float gp = acc_p[mf][nf][i];
        float gt = acc_t[mf][nf][i];
        float gn = gt - gp;
        float diag = (r==c)?0.1f:0.f;
        A0[(size_t)r*D_ + c] = kn*gn + kt*gt - rn*mnr*mnc - rt*mtr*mtc + diag;
        A1[(size_t)r*D_ + c] = kp*gp + kt*gt - rp*mpr*mpc - rt*mtr*mtc + diag;
      }
    }
  }
}

// ---------------- panel-resident left-looking Cholesky, one launch per block-row P ----------------
template<int P>
__global__ __launch_bounds__(512) void k_cholp(float* __restrict__ A,
                                               float* __restrict__ invDT)
{
  constexpr int NA = 7 - P;
  extern __shared__ float sm[];
  float* slab = sm;                    // [64][NA*64] pair-swizzled
  float* B1   = sm + NA*4096;          // [64][68]
  float* B2   = B1 + 4352;             // [64][68]
  float* Ld   = B1;                    // overlay (64x65)
  float* IvT  = B2;                    // overlay (64x68)
  int m, du; decode_mt(blockIdx.x, 1, m, du); (void)du;
  int t = threadIdx.x, tr = t&15, tc2 = t>>4;
  float* Am = A + (size_t)m*D_*D_;
  const float* prow = Am + (size_t)(P*NB)*D_;

  float accd[4][2];
  float acco[(NA>0)?NA:1][4][2];

  // ---- init: stage block-row P, pull into regs ----
  stage68(prow + P*NB, D_, B2, t);
  __syncthreads();
  #pragma unroll
  for (int u=0;u<4;u++){
    accd[u][0] = B2[(tr*4+u)*68 + tc2*2];
    accd[u][1] = B2[(tr*4+u)*68 + tc2*2 + 1];
  }
  __syncthreads();
  #pragma unroll
  for (int a=0;a<NA;a++){
    stage68(prow + (P+1+a)*NB, D_, B2, t);
    __syncthreads();
    #pragma unroll
    for (int u=0;u<4;u++){
      acco[a][u][0] = B2[(tr*4+u)*68 + tc2*2];
      acco[a][u][1] = B2[(tr*4+u)*68 + tc2*2 + 1];
    }
    __syncthreads();
  }

  // ---- history: row P -= U(k,P)^T * U(k, .) ----
  #pragma unroll
  for (int k=0;k<P;k++){
    stage68(Am + (size_t)(k*NB)*D_ + P*NB, D_, B1, t);
    __syncthreads();
    for (int kk=0;kk<64;kk++){
      float4 av = *((const float4*)&B1[kk*68 + tr*4]);
      float2 bv = *((const float2*)&B1[kk*68 + tc2*2]);
      accd[0][0] = fmaf(-av.x, bv.x, accd[0][0]); accd[0][1] = fmaf(-av.x, bv.y, accd[0][1]);
      accd[1][0] = fmaf(-av.y, bv.x, accd[1][0]); accd[1][1] = fmaf(-av.y, bv.y, accd[1][1]);
      accd[2][0] = fmaf(-av.z, bv.x, accd[2][0]); accd[2][1] = fmaf(-av.z, bv.y, accd[2][1]);
      accd[3][0] = fmaf(-av.w, bv.x, accd[3][0]); accd[3][1] = fmaf(-av.w, bv.y, accd[3][1]);
    }
    __syncthreads();
    #pragma unroll
    for (int a=0;a<NA;a++){
      stage68(Am + (size_t)(k*NB)*D_ + (P+1+a)*NB, D_, B2, t);
      __syncthreads();
      for (int kk=0;kk<64;kk++){
        float4 av = *((const float4*)&B1[kk*68 + tr*4]);
        float2 bv = *((const float2*)&B2[kk*68 + tc2*2]);
        acco[a][0][0] = fmaf(-av.x, bv.x, acco[a][0][0]); acco[a][0][1] = fmaf(-av.x, bv.y, acco[a][0][1]);
        acco[a][1][0] = fmaf(-av.y, bv.x, acco[a][1][0]); acco[a][1][1] = fmaf(-av.y, bv.y, acco[a][1][1]);
        acco[a][2][0] = fmaf(-av.z, bv.x, acco[a][2][0]); acco[a][2][1] = fmaf(-av.z, bv.y, acco[a][2][1]);
        acco[a][3][0] = fmaf(-av.w, bv.x, acco[a][3][0]); acco[a][3][1] = fmaf(-av.w, bv.y, acco[a][3][1]);
      }
      __syncthreads();
    }
  }

  // ---- diag factor (Ld overlays B1) ----
  #pragma unroll
  for (int u=0;u<4;u++){
    Ld[(tr*4+u)*65 + tc2*2]   = accd[u][0];
    Ld[(tr*4+u)*65 + tc2*2+1] = accd[u][1];
  }
  for (int l=t; l<4352; l+=512) IvT[l] = 0.f;
  __syncthreads();
  for (int k=0;k<64;k++){
    if (t==0) Ld[k*65+k] = sqrtf(Ld[k*65+k]);
    __syncthreads();
    if (t>k && t<64) Ld[t*65+k] /= Ld[k*65+k];
    __syncthreads();
    for (int l=t; l<4096; l+=512){
      int r = l>>6, c = l&63;
      if (r>k && c>k) Ld[r*65+c] = fmaf(-Ld[r*65+k], Ld[c*65+k], Ld[r*65+c]);
    }
    __syncthreads();
  }
  // ---- triangular inverse: 8 lanes per column, register-resident ----
  {
    int c = t>>3, s = t&7;
    float myv[8];
    #pragma unroll
    for (int i=0;i<8;i++) myv[i] = 0.f;
    float dinv = 1.f/Ld[c*65+c];
    if (s==0) myv[0] = dinv;
    for (int r=c+1;r<64;r++){
      float partial = 0.f;
      #pragma unroll
      for (int idx=0;idx<8;idx++){
        int k2 = c + s + 8*idx;
        if (k2 < r) partial = fmaf(Ld[r*65+k2], myv[idx], partial);
      }
      partial += __shfl_xor(partial, 1, 64);
      partial += __shfl_xor(partial, 2, 64);
      partial += __shfl_xor(partial, 4, 64);
      float val = -partial / Ld[r*65+r];
      int d = r - c;
      #pragma unroll
      for (int idx=0;idx<8;idx++)
        if ((d & 7) == s && (d >> 3) == idx) myv[idx] = val;
    }
    #pragma unroll
    for (int idx=0;idx<8;idx++){
      int k2 = c + s + 8*idx;
      if (k2 < 64) IvT[c*68 + k2] = myv[idx];
    }
  }
  __syncthreads();
  // ---- write invDT and U(P,P)=Ld^T ----
  {
    int r2 = t>>3, seg = (t&7)*8;
    float* Ig = invDT + ((size_t)m*8 + P)*4096;
    *((float4*)&Ig[r2*64+seg])   = *((float4*)&IvT[r2*68+seg]);
    *((float4*)&Ig[r2*64+seg+4]) = *((float4*)&IvT[r2*68+seg+4]);
    float vals[8];
    #pragma unroll
    for (int i=0;i<8;i++){ int c = seg+i; vals[i] = (c >= r2) ? Ld[c*65 + r2] : 0.f; }
    float* Ug = Am + (size_t)(P*NB + r2)*D_ + P*NB + seg;
    *((float4*)&Ug[0]) = make_float4(vals[0],vals[1],vals[2],vals[3]);
    *((float4*)&Ug[4]) = make_float4(vals[4],vals[5],vals[6],vals[7]);
  }

  if (NA > 0){
    // stage acco -> slab (pair-swizzled)
    #pragma unroll
    for (int a=0;a<NA;a++)
      #pragma unroll
      for (int u=0;u<4;u++)
        *pr2(slab, NA*64, tr*4+u, a*32+tc2) = make_float2(acco[a][u][0], acco[a][u][1]);
    __syncthreads();
    // trsm: tile_a <- invD * tile_a
    #pragma unroll
    for (int a=0;a<NA;a++){
      float o2[4][2] = {};
      for (int kk=0;kk<64;kk++){
        float4 av = *((const float4*)&IvT[kk*68 + tr*4]);
        float2 bv = *pr2(slab, NA*64, kk, a*32+tc2);
        o2[0][0] = fmaf(av.x, bv.x, o2[0][0]); o2[0][1] = fmaf(av.x, bv.y, o2[0][1]);
        o2[1][0] = fmaf(av.y, bv.x, o2[1][0]); o2[1][1] = fmaf(av.y, bv.y, o2[1][1]);
        o2[2][0] = fmaf(av.z, bv.x, o2[2][0]); o2[2][1] = fmaf(av.z, bv.y, o2[2][1]);
        o2[3][0] = fmaf(av.w, bv.x, o2[3][0]); o2[3][1] = fmaf(av.w, bv.y, o2[3][1]);
      }
      __syncthreads();
      #pragma unroll
      for (int u=0;u<4;u++)
        *pr2(slab, NA*64, tr*4+u, a*32+tc2) = make_float2(o2[u][0], o2[u][1]);
    }
    __syncthreads();
    // write slab -> global block-row P (off-diag)
    int r2 = t>>3;
    for (int c4 = (t&7); c4 < NA*16; c4 += 8){
      int cc = c4*4;
      float2 x0 = *pr2(slab, NA*64, r2, cc>>1);
      float2 x1 = *pr2(slab, NA*64, r2, (cc>>1)+1);
      *((float4*)(Am + (size_t)(P*NB + r2)*D_ + (P+1)*NB + cc)) = make_float4(x0.x,x0.y,x1.x,x1.y);
    }
  }
}

// ---------------- fused rform + forward solve + maha + logits (Z resident in LDS) ----------------
__global__ __launch_bounds__(512) void k_solvefin(const float* __restrict__ Qs,
                                                  const float* __restrict__ mu,
                                                  const float* __restrict__ A,
                                                  const float* __restrict__ invDT,
                                                  const int* __restrict__ qlen,
                                                  const float* __restrict__ lps,
                                                  float* __restrict__ out)
{
  extern __shared__ float sm[];
  float* Zs = sm;              // [512][64] pair-swizzled
  float* B1 = sm + 512*64;     // [64][68]
  int m, t0; decode_mt(blockIdx.x, 4, m, t0);
  int q0 = t0*NB, b = m>>1, cls = m&1;
  int t = threadIdx.x, tr = t&15, tc2 = t>>4;
  const float* Am = A + (size_t)m*D_*D_;
  const float* muv = mu + ((size_t)b*3 + cls)*D_;
  float cs0 = 0.f, cs1 = 0.f;
  for (int j=0;j<NT;j++){
    float acc[4][2];
    float4 mv = *(const float4*)&muv[j*NB + tr*4];
    {
      const float4 qv0 = *(const float4*)&Qs[((size_t)b*Q_ + q0 + tc2*2 + 0)*D_ + j*NB + tr*4];
      const float4 qv1 = *(const float4*)&Qs[((size_t)b*Q_ + q0 + tc2*2 + 1)*D_ + j*NB + tr*4];
      acc[0][0] = mv.x - qv0.x; acc[0][1] = mv.x - qv1.x;
      acc[1][0] = mv.y - qv0.y; acc[1][1] = mv.y - qv1.y;
      acc[2][0] = mv.z - qv0.z; acc[2][1] = mv.z - qv1.z;
      acc[3][0] = mv.w - qv0.w; acc[3][1] = mv.w - qv1.w;
    }
    for (int k=0;k<j;k++){
      __syncthreads();
      stage68(Am + (size_t)(k*NB)*D_ + j*NB, D_, B1, t);   // U(k,j): OpA[kk][r]=L_jk[r][kk]
      __syncthreads();
      for (int kk=0;kk<64;kk++){
        float4 av = *((const float4*)&B1[kk*68 + tr*4]);
        float2 bv = *pr2(Zs, 64, k*NB + kk, tc2);
        acc[0][0] = fmaf(-av.x, bv.x, acc[0][0]); acc[0][1] = fmaf(-av.x, bv.y, acc[0][1]);
        acc[1][0] = fmaf(-av.y, bv.x, acc[1][0]); acc[1][1] = fmaf(-av.y, bv.y, acc[1][1]);
        acc[2][0] = fmaf(-av.z, bv.x, acc[2][0]); acc[2][1] = fmaf(-av.z, bv.y, acc[2][1]);
        acc[3][0] = fmaf(-av.w, bv.x, acc[3][0]); acc[3][1] = fmaf(-av.w, bv.y, acc[3][1]);
      }
    }
    __syncthreads();
    // stage S into Z_j rows; stage invDT
    #pragma unroll
    for (int u=0;u<4;u++)
      *pr2(Zs, 64, j*NB + tr*4+u, tc2) = make_float2(acc[u][0], acc[u][1]);
    stage68(invDT + ((size_t)m*8 + j)*4096, 64, B1, t);
    __syncthreads();
    float o4[4][2] = {};
    for (int kk=0;kk<64;kk++){
      float4 av = *((const float4*)&B1[kk*68 + tr*4]);
      float2 bv = *pr2(Zs, 64, j*NB + kk, tc2);
      o4[0][0] = fmaf(av.x, bv.x, o4[0][0]); o4[0][1] = fmaf(av.x, bv.y, o4[0][1]);
      o4[1][0] = fmaf(av.y, bv.x, o4[1][0]); o4[1][1] = fmaf(av.y, bv.y, o4[1][1]);
      o4[2][0] = fmaf(av.z, bv.x, o4[2][0]); o4[2][1] = fmaf(av.z, bv.y, o4[2][1]);
      o4[3][0] = fmaf(av.w, bv.x, o4[3][0]); o4[3][1] = fmaf(av.w, bv.y, o4[3][1]);
    }
    __syncthreads();
    #pragma unroll
    for (int u=0;u<4;u++){
      *pr2(Zs, 64, j*NB + tr*4+u, tc2) = make_float2(o4[u][0], o4[u][1]);
      cs0 = fmaf(o4[u][0], o4[u][0], cs0);
      cs1 = fmaf(o4[u][1], o4[u][1], cs1);
    }
  }
  for (int d2=1; d2<16; d2<<=1){
    cs0 += __shfl_xor(cs0, d2, 64);
    cs1 += __shfl_xor(cs1, d2, 64);
  }
  if (tr == 0){
    float s2 = expf(2.f*lps[0]);
    int L = qlen[b];
    int q = q0 + tc2*2;
    out[((size_t)b*Q_ + q)*2 + cls]     = (q   < L) ? -s2*cs0 : 0.f;
    out[((size_t)b*Q_ + q + 1)*2 + cls] = (q+1 < L) ? -s2*cs1 : 0.f;
  }
}

extern "C" void kernel_launch(void* const* d_in, const int* in_sizes, int n_in,
                              void* d_out, int out_size, void* d_ws, size_t ws_size,
                              hipStream_t stream) {
  (void)in_sizes; (void)n_in; (void)out_size;
  const float* X   = (const float*)d_in[0];
  const int*   lab = (const int*)d_in[1];
  const float* Qs  = (const float*)d_in[2];
  const int*   sl  = (const int*)d_in[3];
  const int*   ql  = (const int*)d_in[4];
  const float* lps = (const float*)d_in[5];
  float* out = (float*)d_out;

  float* A  = (float*)d_ws;                            // [512,512,512] f32
  unsigned short* Xvh = (unsigned short*)(A + (size_t)NM_*D_*D_);  // [256,512,512] f16
  unsigned short* Xvl = Xvh + (size_t)B_*D_*S_;
  float* invDT = (float*)(Xvl + (size_t)B_*D_*S_);     // [512,8,64,64] f32 (transposed)
  float* mu   = invDT + (size_t)NM_*8*64*64;           // [256,3,512]
  float* cnt  = mu + (size_t)B_*3*D_;                  // [256,2]
  unsigned int* wpbits = (unsigned int*)(cnt + B_*2);  // [256,16]
  size_t need = (size_t)((char*)(wpbits + B_*16) - (char*)d_ws);
  if (ws_size < need) return;

  k_stats<<<dim3(B_), dim3(TPB), 0, stream>>>(X, lab, sl, mu, cnt, wpbits);
  k_prep<<<dim3(64, B_), dim3(TPB), 0, stream>>>(X, sl, Xvh, Xvl);
  k_gram<<<dim3(2560), dim3(TPB), 0, stream>>>(Xvh, Xvl, wpbits, mu, cnt, sl, A);

  #define SHL(na) ((size_t)((na)*4096 + 2*4352) * sizeof(float))
  k_cholp<0><<<dim3(NM_), dim3(512), SHL(7), stream>>>(A, invDT);
  k_cholp<1><<<dim3(NM_), dim3(512), SHL(6), stream>>>(A, invDT);
  k_cholp<2><<<dim3(NM_), dim3(512), SHL(5), stream>>>(A, invDT);
  k_cholp<3><<<dim3(NM_), dim3(512), SHL(4), stream>>>(A, invDT);
  k_cholp<4><<<dim3(NM_), dim3(512), SHL(3), stream>>>(A, invDT);
  k_cholp<5><<<dim3(NM_), dim3(512), SHL(2), stream>>>(A, invDT);
  k_cholp<6><<<dim3(NM_), dim3(512), SHL(1), stream>>>(A, invDT);
  k_cholp<7><<<dim3(NM_), dim3(512), SHL(0), stream>>>(A, invDT);
  #undef SHL

  size_t shl2 = (size_t)(512*64 + 64*68) * sizeof(float);
  k_solvefin<<<dim3(NM_*4), dim3(512), shl2, stream>>>(Qs, mu, A, invDT, ql, lps, out);
}